// Round 1
// 672.006 us; speedup vs baseline: 1.0029x; 1.0029x over previous
//
#include <hip/hip_runtime.h>

// out[b, c, n] = mean[v] + dot(basis[v, :], texcode[b, :])
//   v = 3072*y[n] + 6*x[n] + (2 - c)
//   x[n] = clip(int(uv[n,0]*256), 0, 255)
//   y[n] = clip(int((1-uv[n,1])*256), 0, 255)
//
// Structure: 256-thread block = 4 waves; each wave handles one pair p = 3n+c.
// Lane = kg*8 + b: kg in [0,8) splits K, b in [0,8) is the batch.
//
// v2 changes vs v1 (theory: kernel is instruction-bound, not BW-bound):
//  - K split as interleaved float4 chunks: lane kg covers float4 indices
//    j = i*8 + kg (i=0..5 -> k 0..191) + scalar k = 192+kg. Basis row read
//    becomes 6x global_load_dwordx4 (each wave-instruction touches one
//    contiguous 128 B slab) + 1 dword, vs 25 scalar dword loads.
//  - LDS staging dropped entirely: texcode (6.4 KB) is L1/L2-resident after
//    the first few blocks; direct float4 global loads replace the
//    25-load + 25-ds_write + syncthreads + 25-ds_read round-trip.
//  - uv loaded as float2; mean[v] hoisted early so its latency hides under
//    the dot product.

#define K_SZ 200
#define PAIRS_PER_BLOCK 4

__global__ __launch_bounds__(256) void flametex_sample_kernel(
    const float* __restrict__ texcode,  // (8, 200)
    const float* __restrict__ uv,       // (N, 2)
    const float* __restrict__ mean,     // (786432,)
    const float* __restrict__ basis,    // (786432, 200)
    float* __restrict__ out,            // (8, 3, N)
    int N)
{
    const int tid = threadIdx.x;
    const int p = blockIdx.x * PAIRS_PER_BLOCK + (tid >> 6);  // pair = 3n + c
    if (p >= 3 * N) return;

    const int n = p / 3;
    const int c = p - 3 * n;

    const int lane = tid & 63;
    const int kg   = lane >> 3;   // k-group 0..7
    const int b    = lane & 7;    // batch 0..7

    // Sample coordinates (wave-uniform, 8 B vector load)
    const float2 uvn = reinterpret_cast<const float2*>(uv)[n];
    int xi = (int)(uvn.x * 256.0f);
    xi = min(max(xi, 0), 255);
    int yi = (int)((1.0f - uvn.y) * 256.0f);
    yi = min(max(yi, 0), 255);
    const int v = 3072 * yi + 6 * xi + (2 - c);

    // Issue the mean gather early; broadcast load (same addr across lanes).
    const float mv = mean[v];

    // basis row base is 16B-aligned: v*200 floats = v*800 B, 800 = 50*16.
    // texcode row base: b*200 floats = b*800 B, also 16B-aligned.
    const float4* __restrict__ b4 =
        reinterpret_cast<const float4*>(basis + (long long)v * K_SZ) + kg;
    const float4* __restrict__ t4 =
        reinterpret_cast<const float4*>(texcode + b * K_SZ) + kg;

    float acc = 0.0f;
#pragma unroll
    for (int i = 0; i < 6; ++i) {
        const float4 bb = b4[i * 8];   // contiguous 128 B per wave-instr
        const float4 tt = t4[i * 8];   // L1-hit after first block
        acc += bb.x * tt.x;
        acc += bb.y * tt.y;
        acc += bb.z * tt.z;
        acc += bb.w * tt.w;
    }
    // Remainder k = 192..199: lane kg handles k = 192 + kg
    acc += basis[(long long)v * K_SZ + 192 + kg] * texcode[b * K_SZ + 192 + kg];

    // Butterfly over the kg bits (3, 4, 5) — full K-sum in 3 steps
    acc += __shfl_xor(acc, 8, 64);
    acc += __shfl_xor(acc, 16, 64);
    acc += __shfl_xor(acc, 32, 64);

    if (kg == 0)
        out[((long long)b * 3 + c) * N + n] = mv + acc;
}

extern "C" void kernel_launch(void* const* d_in, const int* in_sizes, int n_in,
                              void* d_out, int out_size, void* d_ws, size_t ws_size,
                              hipStream_t stream) {
    const float* texcode = (const float*)d_in[0];  // (8, 200)
    const float* uv      = (const float*)d_in[1];  // (N, 2)
    const float* mean    = (const float*)d_in[2];  // (1, 1, 786432)
    const float* basis   = (const float*)d_in[3];  // (1, 786432, 200)
    float* out = (float*)d_out;                    // (8, 3, N) float32

    const int N = in_sizes[1] / 2;                 // 5023
    const int total = 3 * N;                       // 15069 pairs
    const int blocks = (total + PAIRS_PER_BLOCK - 1) / PAIRS_PER_BLOCK;

    flametex_sample_kernel<<<blocks, 256, 0, stream>>>(texcode, uv, mean, basis, out, N);
}